// Round 19
// baseline (268.072 us; speedup 1.0000x reference)
//
#include <hip/hip_runtime.h>
#include <hip/hip_fp16.h>

#define BB 4
#define CC 32
#define HH 480
#define WW 640
#define HWv (HH*WW)

typedef _Float16 f16x8 __attribute__((ext_vector_type(8)));
typedef float    f32x4 __attribute__((ext_vector_type(4)));

union H4 { short4 s; __half h[4]; };

// ---------------------------------------------------------------------------
// Kernel A: streaming transpose + fp16 pack for ONE batch:
//   kx_b [32][H][W] f32  ->  T [H][W][32] fp16
// Reads: src = kx_b + tid + c*HW  -> perfectly coalesced per instruction.
// Writes: 64 B per thread, 4x f16x8 stores. Also zeroes the 16B zero-page
// at T + HW*32 (used by conv staging for out-of-bounds lanes).
// ---------------------------------------------------------------------------
__global__ __launch_bounds__(256) void tpose(const float* __restrict__ kx_b,
                                             _Float16* __restrict__ T)
{
    int tid = blockIdx.x * 256 + threadIdx.x;       // 0 .. HWv-1 (one px)
    const float* src = kx_b + tid;
    _Float16* dst = T + (size_t)tid * CC;

    f16x8 o[4];
#pragma unroll
    for (int g = 0; g < 4; ++g) {
#pragma unroll
        for (int j = 0; j < 8; ++j)
            o[g][j] = (_Float16)src[(size_t)(g * 8 + j) * HWv];
    }
#pragma unroll
    for (int g = 0; g < 4; ++g)
        *reinterpret_cast<f16x8*>(dst + g * 8) = o[g];

    if (blockIdx.x == 0 && threadIdx.x == 0) {
        f16x8 z = {};
        *reinterpret_cast<f16x8*>(T + (size_t)HWv * CC) = z;   // zero-page
    }
}

// ---------------------------------------------------------------------------
// Kernel B: 3x3 conv (32->8) + bias + normalization via fp16 MFMA, for ONE
// batch, reading the pixel-major T. Tile 4x64 out; staged region 6 rows x
// 73 px x 32 ch in LDS, layout [ry][ks][x] units of 16B (x-dim 73 spreads
// banks), filled by per-lane-gathered global_load_lds (OOB lanes read the
// zero-page -> zero padding handled with no masks). MFMA/norm/store math
// is R10's (end-to-end verified: absmax stayed at fp16-quantization level).
// Output: K [9][H][W] fp16 for this batch.
// ---------------------------------------------------------------------------
#define CTR 4
#define CTC 64
#define SU  1792              // staged 16B units (6*4*73 = 1752, padded)

__global__ __launch_bounds__(256) void conv_mfma(const _Float16* __restrict__ T,
                                                 const float* __restrict__ Wf,
                                                 const float* __restrict__ bf,
                                                 __half* __restrict__ Kb)
{
    __shared__ _Float16 smem[SU * 8];   // 28672 B

    const int t    = threadIdx.x;
    const int lane = t & 63;
    const int wv   = t >> 6;            // wave 0..3 = output row in tile
    const int n    = lane & 15;         // A-row pixel / B-col out-channel
    const int ks   = lane >> 4;         // k-slice (channels ks*8 .. +7)

    const int xt = blockIdx.x % (WW / CTC);
    const int yt = blockIdx.x / (WW / CTC);
    const int y0 = yt * CTR;
    const int x0 = xt * CTC;

    const _Float16* zpage = T + (size_t)HWv * CC;

    // ---- stage: 28 issues, per-lane gathered source, linear LDS dest ----
    for (int i = wv; i < 28; i += 4) {
        int u  = i * 64 + lane;          // 0..1791
        int x  = u % 73;
        int q  = u / 73;                 // 0..24
        int ksu = q & 3;
        int ry  = q >> 2;                // 0..6 (6 = pad -> zero)
        int gy = y0 - 1 + ry;
        int gx = x0 - 4 + x;
        bool ok = (ry < 6) && (gy >= 0) && (gy < HH) && (gx >= 0) && (gx < WW);
        const _Float16* src = ok ? (T + ((size_t)gy * WW + gx) * CC + ksu * 8)
                                 : zpage;
        __builtin_amdgcn_global_load_lds(
            (const __attribute__((address_space(1))) void*)src,
            (__attribute__((address_space(3))) void*)((char*)smem + i * 1024),
            16, 0, 0);
    }

    // ---- B fragments + bias (one-shot) ----
    f16x8 btap[9];
#pragma unroll
    for (int tp = 0; tp < 9; ++tp) {
#pragma unroll
        for (int j = 0; j < 8; ++j) {
            float w = (n < 8) ? Wf[(n * CC + (ks * 8 + j)) * 9 + tp] : 0.f;
            btap[tp][j] = (_Float16)w;
        }
    }
    const float bfv = (n < 8) ? bf[n] : 0.f;

    __syncthreads();                    // staging complete (vmcnt drained)

    // ---- MFMA: 4 col-groups x 9 taps, K=32 per mfma ----
    f32x4 acc[4];
#pragma unroll
    for (int g = 0; g < 4; ++g) acc[g] = f32x4{bfv, bfv, bfv, bfv};

#pragma unroll
    for (int g = 0; g < 4; ++g) {
#pragma unroll
        for (int ty = 0; ty < 3; ++ty) {
#pragma unroll
            for (int tx = 0; tx < 3; ++tx) {
                int xcol = g * 16 + n + tx + 3;        // fetch-region col
                int ryA  = wv + ty;                    // staged row 0..5
                const f16x8* ap = reinterpret_cast<const f16x8*>(
                    (const char*)smem + ((ryA * 4 + ks) * 73 + xcol) * 16);
                acc[g] = __builtin_amdgcn_mfma_f32_16x16x32_f16(
                             *ap, btap[ty * 3 + tx], acc[g], 0, 0, 0);
            }
        }
    }
    __syncthreads();                    // staged tile dead; reuse smem

    // ---- normalize (channels live in lanes n=0..7) + LDS transpose ----
    _Float16* outa = smem;              // [256 px][10 planes]
#pragma unroll
    for (int g = 0; g < 4; ++g) {
        float aff[4], sa[4], ss[4];
#pragma unroll
        for (int r = 0; r < 4; ++r) {
            aff[r] = (n < 8) ? acc[g][r] : 0.f;
            sa[r]  = fabsf(aff[r]);
            ss[r]  = aff[r];
        }
#pragma unroll
        for (int wdt = 1; wdt <= 4; wdt <<= 1) {
#pragma unroll
            for (int r = 0; r < 4; ++r) {
                sa[r] += __shfl_xor(sa[r], wdt);
                ss[r] += __shfl_xor(ss[r], wdt);
            }
        }
#pragma unroll
        for (int r = 0; r < 4; ++r) {
            float rinv = 1.0f / sa[r];
            float av   = aff[r] * rinv;
            float k0   = 1.0f - ss[r] * rinv;
            int px = wv * 64 + g * 16 + ks * 4 + r;    // D row = ks*4+r
            if (n < 8)  outa[px * 10 + n + 1] = (_Float16)av;
            if (n == 0) outa[px * 10 + 0]     = (_Float16)k0;
        }
    }
    __syncthreads();

    // ---- store: thread t -> pixel t (row t>>6, col t&63), 9 planes ----
    __half* Kp = Kb + (size_t)(y0 + (t >> 6)) * WW + x0 + (t & 63);
#pragma unroll
    for (int p = 0; p < 9; ++p)
        Kp[(size_t)p * HWv] = __float2half((float)outa[t * 10 + p]);
}

// ---------------------------------------------------------------------------
// Kernel C: one propagation iteration, templated on x dtype (R16-proven).
// Iter 0: f32 -> fp16;  1..10: fp16 -> fp16;  11: fp16 -> f32 d_out.
// OFFSETS order: (0,0),(0,1),(0,-1),(1,0),(1,1),(1,-1),(-1,0),(-1,1),(-1,-1)
// ---------------------------------------------------------------------------
__device__ __forceinline__ void load_row6(const float* r, bool rowok, bool xm,
                                          bool xpl, float o[6])
{
    if (rowok) {
        float4 v = *reinterpret_cast<const float4*>(r);
        o[0] = xm ? r[-1] : 0.f;
        o[1] = v.x; o[2] = v.y; o[3] = v.z; o[4] = v.w;
        o[5] = xpl ? r[4] : 0.f;
    } else {
#pragma unroll
        for (int q = 0; q < 6; ++q) o[q] = 0.f;
    }
}

__device__ __forceinline__ void load_row6h(const __half* r, bool rowok, bool xm,
                                           bool xpl, float o[6])
{
    if (rowok) {
        H4 u;
        u.s = *reinterpret_cast<const short4*>(r);     // 8 B, aligned
        o[0] = xm ? __half2float(r[-1]) : 0.f;
        o[1] = __half2float(u.h[0]); o[2] = __half2float(u.h[1]);
        o[3] = __half2float(u.h[2]); o[4] = __half2float(u.h[3]);
        o[5] = xpl ? __half2float(r[4]) : 0.f;
    } else {
#pragma unroll
        for (int q = 0; q < 6; ++q) o[q] = 0.f;
    }
}

template <typename TI, typename TO>
__global__ __launch_bounds__(256) void prop(const TI* __restrict__ xin,
                                            const __half* __restrict__ K,
                                            TO* __restrict__ xout)
{
    int tid = blockIdx.x * 256 + threadIdx.x;
    const int XT = WW / 4;
    int x4 = tid % XT;
    int t2 = tid / XT;
    int y  = t2 % HH;
    int b  = t2 / HH;
    if (b >= BB) return;
    int x0 = x4 * 4;

    const bool xm  = (x0 > 0);
    const bool xpl = (x0 + 4 < WW);

    const TI* xb = xin + (size_t)b * HWv + (size_t)y * WW + x0;
    float rm[6], r0[6], rp[6];
    if constexpr (sizeof(TI) == 4) {
        load_row6((const float*)xb - WW, y > 0,      xm, xpl, rm);
        load_row6((const float*)xb,      true,       xm, xpl, r0);
        load_row6((const float*)xb + WW, y < HH - 1, xm, xpl, rp);
    } else {
        load_row6h((const __half*)xb - WW, y > 0,      xm, xpl, rm);
        load_row6h((const __half*)xb,      true,       xm, xpl, r0);
        load_row6h((const __half*)xb + WW, y < HH - 1, xm, xpl, rp);
    }

    const __half* Kb = K + (size_t)b * 9 * HWv + (size_t)y * WW + x0;
    float kv[9][4];
#pragma unroll
    for (int k = 0; k < 9; ++k) {
        H4 u;
        u.s = *reinterpret_cast<const short4*>(Kb + (size_t)k * HWv);  // 8 B
#pragma unroll
        for (int p = 0; p < 4; ++p) kv[k][p] = __half2float(u.h[p]);
    }

    float o4[4];
#pragma unroll
    for (int p = 0; p < 4; ++p) {
        o4[p] = kv[0][p] * r0[p + 1]
              + kv[1][p] * r0[p]
              + kv[2][p] * r0[p + 2]
              + kv[3][p] * rm[p + 1]
              + kv[4][p] * rm[p]
              + kv[5][p] * rm[p + 2]
              + kv[6][p] * rp[p + 1]
              + kv[7][p] * rp[p]
              + kv[8][p] * rp[p + 2];
    }

    TO* ob = xout + (size_t)b * HWv + (size_t)y * WW + x0;
    if constexpr (sizeof(TO) == 4) {
        *reinterpret_cast<float4*>((float*)ob) =
            make_float4(o4[0], o4[1], o4[2], o4[3]);
    } else {
        H4 u;
#pragma unroll
        for (int p = 0; p < 4; ++p) u.h[p] = __float2half(o4[p]);
        *reinterpret_cast<short4*>((__half*)ob) = u.s;
    }
}

// ---------------------------------------------------------------------------
extern "C" void kernel_launch(void* const* d_in, const int* in_sizes, int n_in,
                              void* d_out, int out_size, void* d_ws, size_t ws_size,
                              hipStream_t stream) {
    const float* kx   = (const float*)d_in[0];   // [4,32,480,640]
    const float* x_in = (const float*)d_in[1];   // [4,1,480,640]
    const float* Wf   = (const float*)d_in[2];   // [8,32,3,3]
    const float* bf   = (const float*)d_in[3];   // [8]
    float* out  = (float*)d_out;                 // [4,1,480,640]

    _Float16* Kbuf = (_Float16*)d_ws;                     // 22.12 MB fp16
    _Float16* xh0  = Kbuf + (size_t)9 * BB * HWv;         // 2.46 MB
    _Float16* xh1  = xh0  + (size_t)BB * HWv;             // 2.46 MB
    _Float16* T    = xh1  + (size_t)BB * HWv;             // 19.66 MB + 16 B
    __half* KbufH  = (__half*)Kbuf;
    __half* ping[2] = { (__half*)xh0, (__half*)xh1 };

    // conv path: per-batch transpose (T stays L3-hot) + MFMA conv
    const int tblocks = HWv / 256;                        // 1200
    const int cblocks = (HH / CTR) * (WW / CTC);          // 1200
    for (int b = 0; b < BB; ++b) {
        tpose<<<tblocks, 256, 0, stream>>>(kx + (size_t)b * CC * HWv, T);
        conv_mfma<<<cblocks, 256, 0, stream>>>(T, Wf, bf,
                                               KbufH + (size_t)b * 9 * HWv);
    }

    // prop: 12 launches; intermediates fp16 (R16-proven)
    const int pblocks = BB * HH * (WW / 4) / 256;         // 1200
    prop<float, __half><<<pblocks, 256, 0, stream>>>(x_in, KbufH, ping[0]);
    for (int it = 1; it <= 10; ++it) {
        prop<__half, __half><<<pblocks, 256, 0, stream>>>(
            ping[(it - 1) & 1], KbufH, ping[it & 1]);
    }
    prop<__half, float><<<pblocks, 256, 0, stream>>>(ping[0], KbufH, out);
}

// Round 20
// 159.702 us; speedup vs baseline: 1.6786x; 1.6786x over previous
//
#include <hip/hip_runtime.h>
#include <hip/hip_fp16.h>

#define BB 4
#define CC 32
#define HH 480
#define WW 640
#define HWv (HH*WW)

union H8 { __half h[8]; float4 f4; };
union H4 { short4 s; __half h[4]; };

// ---------------------------------------------------------------------------
// Kernel 1: 3x3 conv (32->8) + bias + affinity normalization, fused.
// Exact R9/R16 structure — measured best (108 us). 9 alternative conv
// structures (more ILP, more TLP, branchless, hoisted loads, LDS staging,
// LDS weights, fp16 dot2, MFMA x2) all regressed or tied: the per-channel
// {12 VMEM loads -> waitcnt -> 576 FMA} chain at 2.3 waves/SIMD is the
// HIP-source-level floor for this kernel.
// K stored fp16 (halves prop's dominant traffic; absmax 256 << 1111).
// Output: K [B][9][H][W] fp16, K[0] = 1 - sum(a), K[1..8] = aff_k / sum|aff|
// ---------------------------------------------------------------------------
__global__ __launch_bounds__(128) void conv_gen(const float* __restrict__ kx,
                                                const float* __restrict__ Wf,
                                                const float* __restrict__ bf,
                                                __half* __restrict__ K)
{
    int tid = blockIdx.x * 128 + threadIdx.x;
    const int XT = WW / 8;              // 80 thread-columns
    int x8 = tid % XT;
    int t2 = tid / XT;
    int y  = t2 % HH;
    int b  = t2 / HH;
    if (b >= BB) return;
    int x0 = x8 * 8;

    float acc[8][8];
#pragma unroll
    for (int o = 0; o < 8; ++o) {
        float bv = bf[o];
#pragma unroll
        for (int p = 0; p < 8; ++p) acc[o][p] = bv;
    }

    const float* kxb = kx + (size_t)b * CC * HWv + (size_t)y * WW + x0;
    const bool xm = (x0 > 0);
    const bool xp = (x0 + 8 < WW);

    for (int c = 0; c < CC; ++c) {
        const float* pl = kxb + (size_t)c * HWv;
#pragma unroll
        for (int r = 0; r < 3; ++r) {
            const int dy = r - 1;
            const bool rowok = (y + dy >= 0) && (y + dy < HH);
            const float* rp = pl + dy * WW;
            float row[10];
            if (rowok) {
                float4 v0 = *reinterpret_cast<const float4*>(rp);
                float4 v1 = *reinterpret_cast<const float4*>(rp + 4);
                row[0] = xm ? rp[-1] : 0.f;
                row[1] = v0.x; row[2] = v0.y; row[3] = v0.z; row[4] = v0.w;
                row[5] = v1.x; row[6] = v1.y; row[7] = v1.z; row[8] = v1.w;
                row[9] = xp ? rp[8] : 0.f;
            } else {
#pragma unroll
                for (int q = 0; q < 10; ++q) row[q] = 0.f;
            }
#pragma unroll
            for (int o = 0; o < 8; ++o) {
#pragma unroll
                for (int t = 0; t < 3; ++t) {
                    // wave-uniform index -> s_load -> SGPR operand in v_fma
                    float wv = Wf[((o * CC + c) * 3 + r) * 3 + t];
#pragma unroll
                    for (int p = 0; p < 8; ++p) acc[o][p] += wv * row[p + t];
                }
            }
        }
    }

    // normalization: a = aff / sum|aff|; K0 = 1 - sum(a)
    float k0[8];
#pragma unroll
    for (int p = 0; p < 8; ++p) {
        float asum = 0.f;
#pragma unroll
        for (int o = 0; o < 8; ++o) asum += fabsf(acc[o][p]);
        float rinv = 1.0f / asum;
        float s = 0.f;
#pragma unroll
        for (int o = 0; o < 8; ++o) { acc[o][p] *= rinv; s += acc[o][p]; }
        k0[p] = 1.0f - s;
    }

    size_t base = (size_t)b * 9 * HWv + (size_t)y * WW + x0;
    {
        H8 u;
#pragma unroll
        for (int p = 0; p < 8; ++p) u.h[p] = __float2half(k0[p]);
        *reinterpret_cast<float4*>(K + base) = u.f4;
    }
#pragma unroll
    for (int o = 0; o < 8; ++o) {
        H8 u;
#pragma unroll
        for (int p = 0; p < 8; ++p) u.h[p] = __float2half(acc[o][p]);
        *reinterpret_cast<float4*>(K + base + (size_t)(o + 1) * HWv) = u.f4;
    }
}

// ---------------------------------------------------------------------------
// Kernel 2: one propagation iteration, templated on x dtype (R16-proven;
// at the streaming-BW roofline: ~27 MB/launch @ ~6.3 TB/s effective).
// Iter 0: f32 -> fp16;  1..10: fp16 -> fp16;  11: fp16 -> f32 d_out.
// OFFSETS order: (0,0),(0,1),(0,-1),(1,0),(1,1),(1,-1),(-1,0),(-1,1),(-1,-1)
// ---------------------------------------------------------------------------
__device__ __forceinline__ void load_row6(const float* r, bool rowok, bool xm,
                                          bool xpl, float o[6])
{
    if (rowok) {
        float4 v = *reinterpret_cast<const float4*>(r);
        o[0] = xm ? r[-1] : 0.f;
        o[1] = v.x; o[2] = v.y; o[3] = v.z; o[4] = v.w;
        o[5] = xpl ? r[4] : 0.f;
    } else {
#pragma unroll
        for (int q = 0; q < 6; ++q) o[q] = 0.f;
    }
}

__device__ __forceinline__ void load_row6h(const __half* r, bool rowok, bool xm,
                                           bool xpl, float o[6])
{
    if (rowok) {
        H4 u;
        u.s = *reinterpret_cast<const short4*>(r);     // 8 B, aligned (x0%4==0)
        o[0] = xm ? __half2float(r[-1]) : 0.f;
        o[1] = __half2float(u.h[0]); o[2] = __half2float(u.h[1]);
        o[3] = __half2float(u.h[2]); o[4] = __half2float(u.h[3]);
        o[5] = xpl ? __half2float(r[4]) : 0.f;
    } else {
#pragma unroll
        for (int q = 0; q < 6; ++q) o[q] = 0.f;
    }
}

template <typename TI, typename TO>
__global__ __launch_bounds__(256) void prop(const TI* __restrict__ xin,
                                            const __half* __restrict__ K,
                                            TO* __restrict__ xout)
{
    int tid = blockIdx.x * 256 + threadIdx.x;
    const int XT = WW / 4;
    int x4 = tid % XT;
    int t2 = tid / XT;
    int y  = t2 % HH;
    int b  = t2 / HH;
    if (b >= BB) return;
    int x0 = x4 * 4;

    const bool xm  = (x0 > 0);
    const bool xpl = (x0 + 4 < WW);

    const TI* xb = xin + (size_t)b * HWv + (size_t)y * WW + x0;
    float rm[6], r0[6], rp[6];
    if constexpr (sizeof(TI) == 4) {
        load_row6((const float*)xb - WW, y > 0,      xm, xpl, rm);
        load_row6((const float*)xb,      true,       xm, xpl, r0);
        load_row6((const float*)xb + WW, y < HH - 1, xm, xpl, rp);
    } else {
        load_row6h((const __half*)xb - WW, y > 0,      xm, xpl, rm);
        load_row6h((const __half*)xb,      true,       xm, xpl, r0);
        load_row6h((const __half*)xb + WW, y < HH - 1, xm, xpl, rp);
    }

    const __half* Kb = K + (size_t)b * 9 * HWv + (size_t)y * WW + x0;
    float kv[9][4];
#pragma unroll
    for (int k = 0; k < 9; ++k) {
        H4 u;
        u.s = *reinterpret_cast<const short4*>(Kb + (size_t)k * HWv);  // 8 B
#pragma unroll
        for (int p = 0; p < 4; ++p) kv[k][p] = __half2float(u.h[p]);
    }

    float o4[4];
#pragma unroll
    for (int p = 0; p < 4; ++p) {
        o4[p] = kv[0][p] * r0[p + 1]
              + kv[1][p] * r0[p]
              + kv[2][p] * r0[p + 2]
              + kv[3][p] * rm[p + 1]
              + kv[4][p] * rm[p]
              + kv[5][p] * rm[p + 2]
              + kv[6][p] * rp[p + 1]
              + kv[7][p] * rp[p]
              + kv[8][p] * rp[p + 2];
    }

    TO* ob = xout + (size_t)b * HWv + (size_t)y * WW + x0;
    if constexpr (sizeof(TO) == 4) {
        *reinterpret_cast<float4*>((float*)ob) =
            make_float4(o4[0], o4[1], o4[2], o4[3]);
    } else {
        H4 u;
#pragma unroll
        for (int p = 0; p < 4; ++p) u.h[p] = __float2half(o4[p]);
        *reinterpret_cast<short4*>((__half*)ob) = u.s;
    }
}

// ---------------------------------------------------------------------------
extern "C" void kernel_launch(void* const* d_in, const int* in_sizes, int n_in,
                              void* d_out, int out_size, void* d_ws, size_t ws_size,
                              hipStream_t stream) {
    const float* kx   = (const float*)d_in[0];   // [4,32,480,640]
    const float* x_in = (const float*)d_in[1];   // [4,1,480,640]
    const float* Wf   = (const float*)d_in[2];   // [8,32,3,3]
    const float* bf   = (const float*)d_in[3];   // [8]
    float* out  = (float*)d_out;                 // [4,1,480,640]

    __half* Kbuf = (__half*)d_ws;                         // 22.12 MB fp16
    __half* xh0  = Kbuf + (size_t)9 * BB * HWv;           // 2.46 MB fp16
    __half* xh1  = xh0  + (size_t)BB * HWv;               // 2.46 MB fp16
    __half* ping[2] = { xh0, xh1 };

    // conv: 8 px/thread, block=128 -> 1200 blocks (R9 structure, 108 us)
    const int cthreads = BB * HH * (WW / 8);      // 153600
    conv_gen<<<cthreads / 128, 128, 0, stream>>>(kx, Wf, bf, Kbuf);

    // prop: 12 launches; intermediates fp16
    const int pblocks = BB * HH * (WW / 4) / 256; // 1200

    prop<float, __half><<<pblocks, 256, 0, stream>>>(x_in, Kbuf, ping[0]);
    for (int it = 1; it <= 10; ++it) {
        prop<__half, __half><<<pblocks, 256, 0, stream>>>(
            ping[(it - 1) & 1], Kbuf, ping[it & 1]);
    }
    prop<__half, float><<<pblocks, 256, 0, stream>>>(ping[0], Kbuf, out);
}